// Round 7
// baseline (188.659 us; speedup 1.0000x reference)
//
#include <hip/hip_runtime.h>
#include <hip/hip_bf16.h>

#define NN 8192
#define IN_F 256
#define OF 128
#define NT 512            // NN/16 k-tiles

typedef float  f32x4   __attribute__((ext_vector_type(4)));
typedef short  short4v __attribute__((ext_vector_type(4)));
typedef short  short8v __attribute__((ext_vector_type(8)));
typedef int    int4v   __attribute__((ext_vector_type(4)));

__device__ __forceinline__ unsigned short bf16_bits(float x) {
    __bf16 b = (__bf16)x;
    return __builtin_bit_cast(unsigned short, b);
}

__device__ __forceinline__ f32x4 mfma16(short4v a, short4v b, f32x4 c) {
#if __has_builtin(__builtin_amdgcn_mfma_f32_16x16x16bf16_1k)
    return __builtin_amdgcn_mfma_f32_16x16x16bf16_1k(a, b, c, 0, 0, 0);
#else
    asm("v_mfma_f32_16x16x16_bf16 %0, %1, %2, %0" : "+v"(c) : "v"(a), "v"(b));
    return c;
#endif
}

// ---------------------------------------------------------------------------
// Kernel A: h = X @ W (f32, LDS-staged W).  Emits HtB in MFMA-B-fragment
// order (verified R3):  for h[j][f]:
//   tile=j>>4, g=(j>>2)&3, e=j&3, np=f>>5, o=(f>>4)&1, c=f&15
//   idx = ((tile*4+np)*64 + g*16 + c)*8 + o*4 + e
// Also f_src = h.a[:OF], f_dst = h.a[OF:].
// ---------------------------------------------------------------------------
__global__ __launch_bounds__(256) void gat_prep(
    const float* __restrict__ X, const float* __restrict__ W,
    const float* __restrict__ a, unsigned short* __restrict__ HtB,
    float* __restrict__ f_src, float* __restrict__ f_dst)
{
    __shared__ float Wlds[IN_F * OF];   // 128 KiB
    __shared__ float red_s[32][8];
    __shared__ float red_d[32][8];

    const int t = threadIdx.x;
    {
        const f32x4* Wv = (const f32x4*)W;
        f32x4*       Wl = (f32x4*)Wlds;
        #pragma unroll
        for (int c = 0; c < 32; ++c) Wl[c * 256 + t] = Wv[c * 256 + t];
    }
    __syncthreads();

    const int row = t & 31;
    const int sub = t >> 5;
    const int i   = blockIdx.x * 32 + row;

    f32x4 acc[4] = {};
    const float* xrow = X + (size_t)i * IN_F;

    #pragma unroll 4
    for (int kk = 0; kk < IN_F; kk += 4) {
        f32x4 xv = *(const f32x4*)(xrow + kk);
        #pragma unroll
        for (int e = 0; e < 4; ++e) {
            const f32x4* wr = (const f32x4*)(Wlds + (kk + e) * OF + sub * 16);
            float xs = xv[e];
            #pragma unroll
            for (int c4 = 0; c4 < 4; ++c4) acc[c4] += xs * wr[c4];
        }
    }

    const int tile = i >> 4;
    const int gq   = (i >> 2) & 3;
    const int eq   = i & 3;
    const int np   = sub >> 1;
    const int oo   = sub & 1;

    float ps = 0.f, pd = 0.f;
    #pragma unroll
    for (int c4 = 0; c4 < 4; ++c4) {
        #pragma unroll
        for (int e = 0; e < 4; ++e) {
            float v = acc[c4][e];
            int   c = c4 * 4 + e;
            ps += v * a[sub * 16 + c];
            pd += v * a[OF + sub * 16 + c];
            HtB[(size_t)(((tile * 4 + np) * 64) + gq * 16 + c) * 8 + oo * 4 + eq]
                = bf16_bits(v);
        }
    }
    red_s[row][sub] = ps;
    red_d[row][sub] = pd;
    __syncthreads();
    if (t < 32) {
        float s = 0.f;
        #pragma unroll
        for (int s8 = 0; s8 < 8; ++s8) s += red_s[t][s8];
        f_src[blockIdx.x * 32 + t] = s;
    } else if (t < 64) {
        const int r2 = t - 32;
        float s = 0.f;
        #pragma unroll
        for (int s8 = 0; s8 < 8; ++s8) s += red_d[r2][s8];
        f_dst[blockIdx.x * 32 + r2] = s;
    }
}

// ---------------------------------------------------------------------------
// Phase 1: stream adj once; write P (bf16) in MFMA-A-fragment order + rowsums.
// Grid 512 blocks (one 16-row tile each) x 512 threads (8 waves).
// Wave w handles kt = w + 8*it (interleaved -> sequential line order per row).
// Lane (r=lane&15, g=lane>>4) covers row rt*16+r, k = kt*16 + g*4 + e.
// P fragment write: Pv[(rt*NT + kt)*64 + lane] (short4) -> 512B/wave contiguous.
// ---------------------------------------------------------------------------
__global__ __launch_bounds__(512) void gat_scores(
    const int* __restrict__ adj, const float* __restrict__ f_src,
    const float* __restrict__ f_dst, short4v* __restrict__ Pv,
    float* __restrict__ rowsum)
{
    __shared__ float psums[8][16];

    const int tid  = threadIdx.x;
    const int wave = tid >> 6;
    const int lane = tid & 63;
    const int r    = lane & 15;
    const int g    = lane >> 4;
    const int rt   = blockIdx.x;
    const int row  = rt * 16 + r;

    const float fsrc_r = f_src[row];
    const int* aptr = adj + (size_t)row * NN + g * 4;

    float psum = 0.f;

    // depth-2 pipeline on the adj HBM stream
    int4v a0 = *(const int4v*)(aptr + (wave + 0) * 16);
    int4v a1 = *(const int4v*)(aptr + (wave + 8) * 16);

    for (int it = 0; it < 64; ++it) {
        const int kt = wave + it * 8;

        const f32x4 fd = *(const f32x4*)(f_dst + kt * 16 + g * 4);

        const int4v ac = a0;
        a0 = a1;
        const int nk = (it + 2 < 64) ? kt + 16 : kt;
        a1 = *(const int4v*)(aptr + nk * 16);

        float p[4];
        #pragma unroll
        for (int e = 0; e < 4; ++e) {
            float s = fsrc_r + fd[e];
            s = s > 0.f ? s : 0.2f * s;              // leaky_relu
            p[e] = (ac[e] != 0) ? __expf(s) : 0.f;
        }
        psum += (p[0] + p[1]) + (p[2] + p[3]);

        short4v pk = { (short)bf16_bits(p[0]), (short)bf16_bits(p[1]),
                       (short)bf16_bits(p[2]), (short)bf16_bits(p[3]) };
        Pv[(size_t)(rt * NT + kt) * 64 + lane] = pk;
    }

    // reduce psum over the 4 g-groups -> per-row partial for this wave
    psum += __shfl_xor(psum, 16, 64);
    psum += __shfl_xor(psum, 32, 64);
    if (lane < 16) psums[wave][lane] = psum;
    __syncthreads();
    if (tid < 16) {
        float s = 0.f;
        #pragma unroll
        for (int w = 0; w < 8; ++w) s += psums[w][tid];
        rowsum[rt * 16 + tid] = s;
    }
}

// ---------------------------------------------------------------------------
// Phase 2: part[ks] = P_slab @ H  (k-split GEMM, partials to ws).
// Grid = 64 row-blocks x 8 k-splits = 512 blocks x 512 threads (8 waves).
// Wave = one 16-row tile; block's k-range = ks*1024..+1023 (64 kt).
// B (HtB) staged in LDS per 16-kt superstep by all 512 threads -> HtB total
// read = 512 blocks * 256 KB = 128 MB (no per-wave fan-out).
// A (P fragments) = depth-2 register-pipelined 512B contiguous stream.
// Epilogue: per-wave LDS transpose -> row-major partial, coalesced f32x4.
// ---------------------------------------------------------------------------
__global__ __launch_bounds__(512) void gat_pv(
    const short4v* __restrict__ Pv, const short8v* __restrict__ htv,
    float* __restrict__ part)
{
    __shared__ short8v ldsb[4096];   // 64 KiB

    const int tid  = threadIdx.x;
    const int wave = tid >> 6;
    const int lane = tid & 63;
    const int rb   = blockIdx.x >> 3;
    const int ks   = blockIdx.x & 7;
    const int rt   = rb * 8 + wave;          // global 16-row tile

    f32x4 acc[8] = {};

    // A-stream base: 64 consecutive kt starting at ks*64
    const size_t abase = ((size_t)rt * NT + ks * 64) * 64 + lane;
    short4v a0 = Pv[abase];
    short4v a1 = Pv[abase + 64];

    for (int super = 0; super < 4; ++super) {
        // cooperative LDS stage of 16 kt of HtB (64 KiB)
        const size_t sbase = (size_t)(ks * 64 + super * 16) * 256;
        #pragma unroll
        for (int rr = 0; rr < 8; ++rr)
            ldsb[tid + rr * 512] = htv[sbase + tid + rr * 512];
        __syncthreads();

        #pragma unroll 4
        for (int ktl = 0; ktl < 16; ++ktl) {
            const int kt = super * 16 + ktl;

            const short4v af = a0;
            a0 = a1;
            const int nk = (kt + 2 < 64) ? kt + 2 : kt;
            a1 = Pv[abase + (size_t)nk * 64];

            const short8v b0 = ldsb[(ktl * 4 + 0) * 64 + lane];
            const short8v b1 = ldsb[(ktl * 4 + 1) * 64 + lane];
            const short8v b2 = ldsb[(ktl * 4 + 2) * 64 + lane];
            const short8v b3 = ldsb[(ktl * 4 + 3) * 64 + lane];

            acc[0] = mfma16(af, __builtin_shufflevector(b0, b0, 0, 1, 2, 3), acc[0]);
            acc[1] = mfma16(af, __builtin_shufflevector(b0, b0, 4, 5, 6, 7), acc[1]);
            acc[2] = mfma16(af, __builtin_shufflevector(b1, b1, 0, 1, 2, 3), acc[2]);
            acc[3] = mfma16(af, __builtin_shufflevector(b1, b1, 4, 5, 6, 7), acc[3]);
            acc[4] = mfma16(af, __builtin_shufflevector(b2, b2, 0, 1, 2, 3), acc[4]);
            acc[5] = mfma16(af, __builtin_shufflevector(b2, b2, 4, 5, 6, 7), acc[5]);
            acc[6] = mfma16(af, __builtin_shufflevector(b3, b3, 0, 1, 2, 3), acc[6]);
            acc[7] = mfma16(af, __builtin_shufflevector(b3, b3, 4, 5, 6, 7), acc[7]);
        }
        __syncthreads();
    }

    // epilogue: wave-private LDS transpose (frag -> row-major 16x128)
    float* lt = (float*)&ldsb[wave * 512];   // 8 KiB per wave
    #pragma unroll
    for (int nf = 0; nf < 8; ++nf)
        #pragma unroll
        for (int q = 0; q < 4; ++q)
            lt[(4 * (lane >> 4) + q) * OF + nf * 16 + (lane & 15)] = acc[nf][q];

    float* pbase = part + ((size_t)ks * NN + rt * 16) * OF;
    #pragma unroll
    for (int j = 0; j < 8; ++j) {
        const int idx = j * 64 + lane;
        const f32x4 v = *(const f32x4*)&lt[idx * 4];
        *(f32x4*)(pbase + idx * 4) = v;
    }
}

// ---------------------------------------------------------------------------
// Phase 3: out = relu( (sum_ks part[ks]) / rowsum ).  512x512 grid-stride-free.
// ---------------------------------------------------------------------------
__global__ __launch_bounds__(512) void gat_finish(
    const float* __restrict__ part, const float* __restrict__ rowsum,
    float* __restrict__ out)
{
    const int tg  = blockIdx.x * 512 + threadIdx.x;   // f32x4 index
    const int row = tg >> 5;

    f32x4 v = {};
    #pragma unroll
    for (int ks = 0; ks < 8; ++ks)
        v += *(const f32x4*)(part + (size_t)ks * NN * OF + (size_t)tg * 4);

    const float inv = 1.0f / rowsum[row];
    f32x4 o = v * inv;
    #pragma unroll
    for (int e = 0; e < 4; ++e) o[e] = fmaxf(o[e], 0.f);
    *(f32x4*)(out + (size_t)tg * 4) = o;
}

extern "C" void kernel_launch(void* const* d_in, const int* in_sizes, int n_in,
                              void* d_out, int out_size, void* d_ws, size_t ws_size,
                              hipStream_t stream) {
    const float* X   = (const float*)d_in[0];
    const int*   adj = (const int*)d_in[1];
    const float* W   = (const float*)d_in[2];
    const float* a   = (const float*)d_in[3];
    float* out = (float*)d_out;

    char* ws = (char*)d_ws;
    unsigned short* HtB    = (unsigned short*)ws;                    // 2 MiB
    float*          f_src  = (float*)(ws + 2097152);                 // 32 KiB
    float*          f_dst  = (float*)(ws + 2097152 + 32768);         // 32 KiB
    float*          rowsum = (float*)(ws + 2097152 + 65536);         // 32 KiB
    short4v*        Pv     = (short4v*)(ws + 2195456);               // 128 MiB
    float*          part   = (float*)(ws + 2195456 + 134217728);     // 32 MiB

    gat_prep<<<NN / 32, 256, 0, stream>>>(X, W, a, HtB, f_src, f_dst);
    gat_scores<<<NT, 512, 0, stream>>>(adj, f_src, f_dst, Pv, rowsum);
    gat_pv<<<512, 512, 0, stream>>>(Pv, (const short8v*)HtB, part);
    gat_finish<<<512, 512, 0, stream>>>(part, rowsum, out);
}

// Round 8
// 156.533 us; speedup vs baseline: 1.2052x; 1.2052x over previous
//
#include <hip/hip_runtime.h>
#include <hip/hip_bf16.h>

#define NN 8192
#define IN_F 256
#define OF 128
#define NT 512            // NN/16 k-tiles

typedef float  f32x4   __attribute__((ext_vector_type(4)));
typedef short  short4v __attribute__((ext_vector_type(4)));
typedef short  short8v __attribute__((ext_vector_type(8)));
typedef int    int4v   __attribute__((ext_vector_type(4)));
typedef unsigned long long u64;

__device__ __forceinline__ unsigned short bf16_bits(float x) {
    __bf16 b = (__bf16)x;
    return __builtin_bit_cast(unsigned short, b);
}

__device__ __forceinline__ f32x4 mfma16(short4v a, short4v b, f32x4 c) {
#if __has_builtin(__builtin_amdgcn_mfma_f32_16x16x16bf16_1k)
    return __builtin_amdgcn_mfma_f32_16x16x16bf16_1k(a, b, c, 0, 0, 0);
#else
    asm("v_mfma_f32_16x16x16_bf16 %0, %1, %2, %0" : "+v"(c) : "v"(a), "v"(b));
    return c;
#endif
}

// ---------------------------------------------------------------------------
// Kernel A: h = X @ W (f32, LDS-staged W).  Emits HtB in MFMA-B-fragment
// order (verified R3):  for h[j][f]:
//   tile=j>>4, g=(j>>2)&3, e=j&3, np=f>>5, o=(f>>4)&1, c=f&15
//   idx = ((tile*4+np)*64 + g*16 + c)*8 + o*4 + e
// Also f_src = h.a[:OF], f_dst = h.a[OF:].
// ---------------------------------------------------------------------------
__global__ __launch_bounds__(256) void gat_prep(
    const float* __restrict__ X, const float* __restrict__ W,
    const float* __restrict__ a, unsigned short* __restrict__ HtB,
    float* __restrict__ f_src, float* __restrict__ f_dst)
{
    __shared__ float Wlds[IN_F * OF];   // 128 KiB
    __shared__ float red_s[32][8];
    __shared__ float red_d[32][8];

    const int t = threadIdx.x;
    {
        const f32x4* Wv = (const f32x4*)W;
        f32x4*       Wl = (f32x4*)Wlds;
        #pragma unroll
        for (int c = 0; c < 32; ++c) Wl[c * 256 + t] = Wv[c * 256 + t];
    }
    __syncthreads();

    const int row = t & 31;
    const int sub = t >> 5;
    const int i   = blockIdx.x * 32 + row;

    f32x4 acc[4] = {};
    const float* xrow = X + (size_t)i * IN_F;

    #pragma unroll 4
    for (int kk = 0; kk < IN_F; kk += 4) {
        f32x4 xv = *(const f32x4*)(xrow + kk);
        #pragma unroll
        for (int e = 0; e < 4; ++e) {
            const f32x4* wr = (const f32x4*)(Wlds + (kk + e) * OF + sub * 16);
            float xs = xv[e];
            #pragma unroll
            for (int c4 = 0; c4 < 4; ++c4) acc[c4] += xs * wr[c4];
        }
    }

    const int tile = i >> 4;
    const int gq   = (i >> 2) & 3;
    const int eq   = i & 3;
    const int np   = sub >> 1;
    const int oo   = sub & 1;

    float ps = 0.f, pd = 0.f;
    #pragma unroll
    for (int c4 = 0; c4 < 4; ++c4) {
        #pragma unroll
        for (int e = 0; e < 4; ++e) {
            float v = acc[c4][e];
            int   c = c4 * 4 + e;
            ps += v * a[sub * 16 + c];
            pd += v * a[OF + sub * 16 + c];
            HtB[(size_t)(((tile * 4 + np) * 64) + gq * 16 + c) * 8 + oo * 4 + eq]
                = bf16_bits(v);
        }
    }
    red_s[row][sub] = ps;
    red_d[row][sub] = pd;
    __syncthreads();
    if (t < 32) {
        float s = 0.f;
        #pragma unroll
        for (int s8 = 0; s8 < 8; ++s8) s += red_s[t][s8];
        f_src[blockIdx.x * 32 + t] = s;
    } else if (t < 64) {
        const int r2 = t - 32;
        float s = 0.f;
        #pragma unroll
        for (int s8 = 0; s8 < 8; ++s8) s += red_d[r2][s8];
        f_dst[blockIdx.x * 32 + r2] = s;
    }
}

// ---------------------------------------------------------------------------
// gat_pack: adj (int32 0/1, 256 MB) -> bitmask (8 MB).  Pure stream.
// 2048 blocks x 256 threads (4 waves); wave = one row; 32 iters x 256 cols.
// Lane l loads col c0+l (+64,+128,+192): 4 coalesced 256B dword loads,
// __ballot packs 64 cols -> u64 in column order; lane 0 stores 4 u64 (32B).
// bits viewed as ushort[8192][512]: ushort[i][kt] bit (g*4+e) = adj[i][kt*16+g*4+e].
// ---------------------------------------------------------------------------
__global__ __launch_bounds__(256) void gat_pack(
    const int* __restrict__ adj, u64* __restrict__ bits)
{
    const int tid  = threadIdx.x;
    const int wave = tid >> 6;
    const int lane = tid & 63;
    const int row  = blockIdx.x * 4 + wave;

    const int* arow = adj + (size_t)row * NN + lane;
    u64* brow = bits + (size_t)row * (NN / 64);

    #pragma unroll 2
    for (int it = 0; it < 32; ++it) {
        const int c0 = it * 256;
        const int v0 = arow[c0];
        const int v1 = arow[c0 + 64];
        const int v2 = arow[c0 + 128];
        const int v3 = arow[c0 + 192];
        const u64 m0 = __ballot(v0 != 0);
        const u64 m1 = __ballot(v1 != 0);
        const u64 m2 = __ballot(v2 != 0);
        const u64 m3 = __ballot(v3 != 0);
        if (lane == 0) {
            brow[it * 4 + 0] = m0;
            brow[it * 4 + 1] = m1;
            brow[it * 4 + 2] = m2;
            brow[it * 4 + 3] = m3;
        }
    }
}

// ---------------------------------------------------------------------------
// Kernel B v8: flash-GAT with cache-resident inputs only (no HBM stream).
// 512 blocks x 512 threads (8 waves), 16 rows/block; wave jw strides kt by 8.
// Per iter: 2B adj-bit broadcast load (L1), 4x 1KB HtB fragment loads (L2-hot,
// 2MB total, no adj stream evicting it), f_dst 16B.  Full 128 features per
// wave -> exp computed exactly once per (i,j).  Fragments verified R3.
// ---------------------------------------------------------------------------
__global__ __launch_bounds__(512, 4) void gat_flash(
    const unsigned short* __restrict__ adjbits, const short8v* __restrict__ htv,
    const float* __restrict__ f_src, const float* __restrict__ f_dst,
    float* __restrict__ out)
{
    __shared__ float red[8][16][OF];   // 64 KiB
    __shared__ float rden[8][16];

    const int tid  = threadIdx.x;
    const int jw   = tid >> 6;
    const int lane = tid & 63;
    const int r    = lane & 15;
    const int g    = lane >> 4;
    const int rowbase = blockIdx.x * 16;
    const int row  = rowbase + r;
    const int gs   = g * 4;

    const float fsrc_r = f_src[row];
    const unsigned short* bptr = adjbits + (size_t)row * NT;

    f32x4 acc[8] = {};
    float psum = 0.f;

    for (int it = 0; it < 64; ++it) {
        const int kt = jw + it * 8;

        const unsigned int b16 = bptr[kt];
        const f32x4 fd = *(const f32x4*)(f_dst + kt * 16 + gs);

        const short8v b0 = htv[(size_t)(kt * 4 + 0) * 64 + lane];
        const short8v b1 = htv[(size_t)(kt * 4 + 1) * 64 + lane];
        const short8v b2 = htv[(size_t)(kt * 4 + 2) * 64 + lane];
        const short8v b3 = htv[(size_t)(kt * 4 + 3) * 64 + lane];

        const unsigned int sh = b16 >> gs;
        float p[4];
        #pragma unroll
        for (int e = 0; e < 4; ++e) {
            float s = fsrc_r + fd[e];
            s = s > 0.f ? s : 0.2f * s;              // leaky_relu
            p[e] = (sh & (1u << e)) ? __expf(s) : 0.f;
        }
        psum += (p[0] + p[1]) + (p[2] + p[3]);
        short4v af = { (short)bf16_bits(p[0]), (short)bf16_bits(p[1]),
                       (short)bf16_bits(p[2]), (short)bf16_bits(p[3]) };

        acc[0] = mfma16(af, __builtin_shufflevector(b0, b0, 0, 1, 2, 3), acc[0]);
        acc[1] = mfma16(af, __builtin_shufflevector(b0, b0, 4, 5, 6, 7), acc[1]);
        acc[2] = mfma16(af, __builtin_shufflevector(b1, b1, 0, 1, 2, 3), acc[2]);
        acc[3] = mfma16(af, __builtin_shufflevector(b1, b1, 4, 5, 6, 7), acc[3]);
        acc[4] = mfma16(af, __builtin_shufflevector(b2, b2, 0, 1, 2, 3), acc[4]);
        acc[5] = mfma16(af, __builtin_shufflevector(b2, b2, 4, 5, 6, 7), acc[5]);
        acc[6] = mfma16(af, __builtin_shufflevector(b3, b3, 0, 1, 2, 3), acc[6]);
        acc[7] = mfma16(af, __builtin_shufflevector(b3, b3, 4, 5, 6, 7), acc[7]);
    }

    // denom: reduce psum over the 4 g-groups
    psum += __shfl_xor(psum, 16, 64);
    psum += __shfl_xor(psum, 32, 64);
    if (lane < 16) rden[jw][lane] = psum;

    #pragma unroll
    for (int nf = 0; nf < 8; ++nf)
        #pragma unroll
        for (int q = 0; q < 4; ++q)
            red[jw][g * 4 + q][nf * 16 + r] = acc[nf][q];
    __syncthreads();

    // epilogue: 512 threads x 1 f32x4 = 16x128 tile
    const int orow = tid >> 5;     // 0..15
    const int cg   = tid & 31;     // 4-col group
    f32x4 v = {};
    float den = 0.f;
    #pragma unroll
    for (int w = 0; w < 8; ++w) {
        v   += *(const f32x4*)&red[w][orow][cg * 4];
        den += rden[w][orow];
    }
    const float inv = 1.0f / den;
    f32x4 o = v * inv;
    #pragma unroll
    for (int e = 0; e < 4; ++e) o[e] = fmaxf(o[e], 0.f);
    *(f32x4*)(out + (size_t)(rowbase + orow) * OF + cg * 4) = o;
}

extern "C" void kernel_launch(void* const* d_in, const int* in_sizes, int n_in,
                              void* d_out, int out_size, void* d_ws, size_t ws_size,
                              hipStream_t stream) {
    const float* X   = (const float*)d_in[0];
    const int*   adj = (const int*)d_in[1];
    const float* W   = (const float*)d_in[2];
    const float* a   = (const float*)d_in[3];
    float* out = (float*)d_out;

    char* ws = (char*)d_ws;
    unsigned short* HtB   = (unsigned short*)ws;                 // 2 MiB
    float*          f_src = (float*)(ws + 2097152);              // 32 KiB
    float*          f_dst = (float*)(ws + 2097152 + 32768);      // 32 KiB
    u64*            bits  = (u64*)(ws + 2097152 + 98304);        // 8 MiB

    // pack first (streams adj through L2), then prep (leaves HtB L2-hot)
    gat_pack<<<NN / 4, 256, 0, stream>>>(adj, bits);
    gat_prep<<<NN / 32, 256, 0, stream>>>(X, W, a, HtB, f_src, f_dst);
    gat_flash<<<NN / 16, 512, 0, stream>>>((const unsigned short*)bits,
                                           (const short8v*)HtB, f_src, f_dst, out);
}

// Round 9
// 140.149 us; speedup vs baseline: 1.3461x; 1.1169x over previous
//
#include <hip/hip_runtime.h>
#include <hip/hip_bf16.h>

#define NN 8192
#define IN_F 256
#define OF 128

typedef float  f32x4   __attribute__((ext_vector_type(4)));
typedef short  short4v __attribute__((ext_vector_type(4)));
typedef short  short8v __attribute__((ext_vector_type(8)));
typedef int    int4v   __attribute__((ext_vector_type(4)));

__device__ __forceinline__ unsigned short bf16_bits(float x) {
    __bf16 b = (__bf16)x;
    return __builtin_bit_cast(unsigned short, b);
}

__device__ __forceinline__ f32x4 mfma16(short4v a, short4v b, f32x4 c) {
#if __has_builtin(__builtin_amdgcn_mfma_f32_16x16x16bf16_1k)
    return __builtin_amdgcn_mfma_f32_16x16x16bf16_1k(a, b, c, 0, 0, 0);
#else
    asm("v_mfma_f32_16x16x16_bf16 %0, %1, %2, %0" : "+v"(c) : "v"(a), "v"(b));
    return c;
#endif
}

// async global->LDS, 16B per lane; LDS dest = wave-uniform base + lane*16
__device__ __forceinline__ void gload_lds16(const void* gsrc, void* lds) {
    __builtin_amdgcn_global_load_lds(
        (const __attribute__((address_space(1))) int*)gsrc,
        (__attribute__((address_space(3))) int*)lds, 16, 0, 0);
}

// ---------------------------------------------------------------------------
// Kernel A: h = X @ W (f32, LDS-staged W).  Emits HtB in MFMA-B-fragment
// order (verified R3+):  for h[j][f]:
//   kt=j>>4, g=(j>>2)&3, e=j&3, np=f>>5, o=(f>>4)&1, c=f&15
//   short index = ((kt*4+np)*64 + g*16 + c)*8 + o*4 + e
// Also f_src = h.a[:OF], f_dst = h.a[OF:].
// ---------------------------------------------------------------------------
__global__ __launch_bounds__(256) void gat_prep(
    const float* __restrict__ X, const float* __restrict__ W,
    const float* __restrict__ a, unsigned short* __restrict__ HtB,
    float* __restrict__ f_src, float* __restrict__ f_dst)
{
    __shared__ float Wlds[IN_F * OF];   // 128 KiB
    __shared__ float red_s[32][8];
    __shared__ float red_d[32][8];

    const int t = threadIdx.x;
    {
        const f32x4* Wv = (const f32x4*)W;
        f32x4*       Wl = (f32x4*)Wlds;
        #pragma unroll
        for (int c = 0; c < 32; ++c) Wl[c * 256 + t] = Wv[c * 256 + t];
    }
    __syncthreads();

    const int row = t & 31;
    const int sub = t >> 5;
    const int i   = blockIdx.x * 32 + row;

    f32x4 acc[4] = {};
    const float* xrow = X + (size_t)i * IN_F;

    #pragma unroll 4
    for (int kk = 0; kk < IN_F; kk += 4) {
        f32x4 xv = *(const f32x4*)(xrow + kk);
        #pragma unroll
        for (int e = 0; e < 4; ++e) {
            const f32x4* wr = (const f32x4*)(Wlds + (kk + e) * OF + sub * 16);
            float xs = xv[e];
            #pragma unroll
            for (int c4 = 0; c4 < 4; ++c4) acc[c4] += xs * wr[c4];
        }
    }

    const int kt = i >> 4;
    const int gq = (i >> 2) & 3;
    const int eq = i & 3;
    const int np = sub >> 1;
    const int oo = sub & 1;

    float ps = 0.f, pd = 0.f;
    #pragma unroll
    for (int c4 = 0; c4 < 4; ++c4) {
        #pragma unroll
        for (int e = 0; e < 4; ++e) {
            float v = acc[c4][e];
            int   c = c4 * 4 + e;
            ps += v * a[sub * 16 + c];
            pd += v * a[OF + sub * 16 + c];
            HtB[(size_t)(((kt * 4 + np) * 64) + gq * 16 + c) * 8 + oo * 4 + eq]
                = bf16_bits(v);
        }
    }
    red_s[row][sub] = ps;
    red_d[row][sub] = pd;
    __syncthreads();
    if (t < 32) {
        float s = 0.f;
        #pragma unroll
        for (int s8 = 0; s8 < 8; ++s8) s += red_s[t][s8];
        f_src[blockIdx.x * 32 + t] = s;
    } else if (t < 64) {
        const int r2 = t - 32;
        float s = 0.f;
        #pragma unroll
        for (int s8 = 0; s8 < 8; ++s8) s += red_d[r2][s8];
        f_dst[blockIdx.x * 32 + r2] = s;
    }
}

// ---------------------------------------------------------------------------
// Kernel B v9: flash-GAT with async LDS-staged B (canonical §5 structure).
// 512 blocks x 512 threads (8 waves), 16 rows/block, 2 blocks/CU.
// 64 supersteps of 8 kt; per superstep:
//   - all threads async-stage next 32KB HtB slab into LDS (global_load_lds,
//     double-buffered; the one prefetch the compiler can't sink)
//   - wave w computes kt = s*8+w: adj int4/lane (16 fully-used 64B lines/load,
//     depth-2 registers), exp VALU covers ds_read latency, 8 MFMA.
// adj = the only HBM stream (256MB once) -> ~1600cy/superstep/CU = HBM-bound.
// s0 = blockIdx&63 start-offset rotation decorrelates L2 channel convoys.
// ---------------------------------------------------------------------------
__global__ __launch_bounds__(512, 4) void gat_flash(
    const int* __restrict__ adj, const short8v* __restrict__ htv,
    const float* __restrict__ f_src, const float* __restrict__ f_dst,
    float* __restrict__ out)
{
    __shared__ __align__(16) char smem[66048];
    // [0, 65536): loop = 2 x 32KiB B-stage buffers; epilogue = red[8][16][128]
    // [65536, 66048): rden[8][16]

    const int tid  = threadIdx.x;
    const int w    = tid >> 6;
    const int lane = tid & 63;
    const int r    = lane & 15;
    const int g    = lane >> 4;
    const int rowbase = blockIdx.x * 16;
    const int row  = rowbase + r;
    const int s0   = blockIdx.x & 63;

    const float fsrc_r = f_src[row];
    const int*   aptr = adj + (size_t)row * NN + g * 4;
    const float* fptr = f_dst + g * 4;

    f32x4 acc[8] = {};
    float psum = 0.f;

    // prologue: stage superstep s0 into buf 0
    #pragma unroll
    for (int j = 0; j < 4; ++j) {
        const int u = w * 4 + j;
        gload_lds16(htv + ((size_t)s0 * 32 + u) * 64 + lane, smem + u * 1024);
    }

    // adj / f_dst depth-2 register pipelines
    int4v a_cur = *(const int4v*)(aptr + (s0 * 8 + w) * 16);
    int4v a_nxt = *(const int4v*)(aptr + (((s0 + 1) & 63) * 8 + w) * 16);
    f32x4 f_cur = *(const f32x4*)(fptr + (s0 * 8 + w) * 16);
    f32x4 f_nxt = *(const f32x4*)(fptr + (((s0 + 1) & 63) * 8 + w) * 16);

    int buf = 0;
    for (int ss = 0; ss < 64; ++ss) {
        __syncthreads();   // stage(ss) resident; buf^1 free for overwrite

        // async-stage superstep ss+1 into the other buffer
        if (ss + 1 < 64) {
            const int sn = (s0 + ss + 1) & 63;
            #pragma unroll
            for (int j = 0; j < 4; ++j) {
                const int u = w * 4 + j;
                gload_lds16(htv + ((size_t)sn * 32 + u) * 64 + lane,
                            smem + (buf ^ 1) * 32768 + u * 1024);
            }
        }

        // register-prefetch adj/f_dst for superstep ss+2
        const int kt2 = ((s0 + ss + 2) & 63) * 8 + w;
        const int4v a_new = *(const int4v*)(aptr + kt2 * 16);
        const f32x4 f_new = *(const f32x4*)(fptr + kt2 * 16);

        // this wave's B fragments from LDS (latency covered by exp VALU below)
        const char* lb = smem + buf * 32768 + (w * 4) * 1024 + lane * 16;
        const short8v b0 = *(const short8v*)(lb);
        const short8v b1 = *(const short8v*)(lb + 1024);
        const short8v b2 = *(const short8v*)(lb + 2048);
        const short8v b3 = *(const short8v*)(lb + 3072);

        float p[4];
        #pragma unroll
        for (int e = 0; e < 4; ++e) {
            float s = fsrc_r + f_cur[e];
            s = s > 0.f ? s : 0.2f * s;              // leaky_relu
            p[e] = (a_cur[e] != 0) ? __expf(s) : 0.f;
        }
        psum += (p[0] + p[1]) + (p[2] + p[3]);
        const short4v af = { (short)bf16_bits(p[0]), (short)bf16_bits(p[1]),
                             (short)bf16_bits(p[2]), (short)bf16_bits(p[3]) };

        acc[0] = mfma16(af, __builtin_shufflevector(b0, b0, 0, 1, 2, 3), acc[0]);
        acc[1] = mfma16(af, __builtin_shufflevector(b0, b0, 4, 5, 6, 7), acc[1]);
        acc[2] = mfma16(af, __builtin_shufflevector(b1, b1, 0, 1, 2, 3), acc[2]);
        acc[3] = mfma16(af, __builtin_shufflevector(b1, b1, 4, 5, 6, 7), acc[3]);
        acc[4] = mfma16(af, __builtin_shufflevector(b2, b2, 0, 1, 2, 3), acc[4]);
        acc[5] = mfma16(af, __builtin_shufflevector(b2, b2, 4, 5, 6, 7), acc[5]);
        acc[6] = mfma16(af, __builtin_shufflevector(b3, b3, 0, 1, 2, 3), acc[6]);
        acc[7] = mfma16(af, __builtin_shufflevector(b3, b3, 4, 5, 6, 7), acc[7]);

        a_cur = a_nxt; a_nxt = a_new;
        f_cur = f_nxt; f_nxt = f_new;
        buf ^= 1;
    }

    // denom: reduce psum over the 4 g-groups
    psum += __shfl_xor(psum, 16, 64);
    psum += __shfl_xor(psum, 32, 64);

    __syncthreads();   // all LDS stage reads done; smem becomes red
    float* red  = (float*)smem;                 // [8][16][OF]
    float* rden = (float*)(smem + 65536);       // [8][16]
    if (lane < 16) rden[w * 16 + lane] = psum;
    #pragma unroll
    for (int nf = 0; nf < 8; ++nf)
        #pragma unroll
        for (int q = 0; q < 4; ++q)
            red[((w * 16) + (g * 4 + q)) * OF + nf * 16 + r] = acc[nf][q];
    __syncthreads();

    // epilogue: 512 threads x 1 f32x4 = 16x128 tile
    const int orow = tid >> 5;     // 0..15
    const int cg   = tid & 31;     // 4-col group
    f32x4 v = {};
    float den = 0.f;
    #pragma unroll
    for (int ww = 0; ww < 8; ++ww) {
        v   += *(const f32x4*)&red[((ww * 16) + orow) * OF + cg * 4];
        den += rden[ww * 16 + orow];
    }
    const float inv = 1.0f / den;
    f32x4 o = v * inv;
    #pragma unroll
    for (int e = 0; e < 4; ++e) o[e] = fmaxf(o[e], 0.f);
    *(f32x4*)(out + (size_t)(rowbase + orow) * OF + cg * 4) = o;
}

extern "C" void kernel_launch(void* const* d_in, const int* in_sizes, int n_in,
                              void* d_out, int out_size, void* d_ws, size_t ws_size,
                              hipStream_t stream) {
    const float* X   = (const float*)d_in[0];
    const int*   adj = (const int*)d_in[1];
    const float* W   = (const float*)d_in[2];
    const float* a   = (const float*)d_in[3];
    float* out = (float*)d_out;

    char* ws = (char*)d_ws;
    unsigned short* HtB   = (unsigned short*)ws;                 // 2 MiB
    float*          f_src = (float*)(ws + 2097152);              // 32 KiB
    float*          f_dst = (float*)(ws + 2097152 + 32768);      // 32 KiB

    gat_prep<<<NN / 32, 256, 0, stream>>>(X, W, a, HtB, f_src, f_dst);
    gat_flash<<<NN / 16, 512, 0, stream>>>(adj, (const short8v*)HtB,
                                           f_src, f_dst, out);
}